// Round 1
// baseline (516.144 us; speedup 1.0000x reference)
//
#include <hip/hip_runtime.h>
#include <hip/hip_bf16.h>
#include <stdint.h>

typedef __bf16 bf16;
typedef __bf16 bf16x4 __attribute__((ext_vector_type(4)));
typedef __bf16 bf16x8 __attribute__((ext_vector_type(8)));
typedef float  f32x4  __attribute__((ext_vector_type(4)));

static constexpr int BB = 128;   // batch
static constexpr int TT = 256;   // time
static constexpr int DD = 768;   // input dim
static constexpr int SS = 128;   // state dim
static constexpr int MM = BB * TT;          // 32768 rows
static constexpr int KW1 = DD + SS;         // 896 (k3 K)

// ---------------------------------------------------------------------------
// k0: weight conversion to bf16. W0 = B_w [128][768]; W1 = [D_w | C_w] [768][896]
// ---------------------------------------------------------------------------
__global__ __launch_bounds__(256) void k0_convert(
    const float* __restrict__ B_w, const float* __restrict__ D_w,
    const float* __restrict__ C_w, bf16* __restrict__ W0, bf16* __restrict__ W1) {
  int i = blockIdx.x * 256 + threadIdx.x;           // grid covers exactly 786432
  if (i < SS * DD) {
    W0[i] = (bf16)B_w[i];
  } else {
    int j = i - SS * DD;
    int n = j / KW1;
    int k = j - n * KW1;
    float v = (k < DD) ? D_w[n * DD + k] : C_w[n * SS + (k - DD)];
    W1[j] = (bf16)v;
  }
}

// ---------------------------------------------------------------------------
// GEMM:  C[m][n] = sum_k A[m][k] * W[n][k]   (W row-major [N][K] = "B^T" layout)
// A = kt1 tiles of fp32 (converted) then kt2 tiles of bf16.
// 128x128 tile, BK=64, 256 threads = 4 waves (2x2), 4x4 16x16 frags per wave.
// LDS rows padded to 72 shorts (144B = 9*16B): keeps b128 alignment, kills the
// 16-way column bank conflict (2-way residual = free).
// ---------------------------------------------------------------------------
__global__ __launch_bounds__(256) void k_gemm(
    const float* __restrict__ A1, const bf16* __restrict__ A2,
    const bf16* __restrict__ W, float* __restrict__ C,
    int kt1, int kt2, int lda1, int lda2, int ldb, int ldc) {
  __shared__ __align__(16) bf16 As[128][72];
  __shared__ __align__(16) bf16 Bs[128][72];

  const int tid = threadIdx.x;
  const int lane = tid & 63;
  const int wv = tid >> 6;
  const int wr = wv >> 1, wc = wv & 1;
  const int lr = lane & 15, lh = lane >> 4;
  const int bn0 = blockIdx.x * 128;
  const int bm0 = blockIdx.y * 128;

  f32x4 acc[4][4] = {};
  const int KT = kt1 + kt2;

  for (int kt = 0; kt < KT; ++kt) {
    __syncthreads();
    // ---- stage A tile (128 x 64) ----
    if (kt < kt1) {
      const float* Ab = A1 + (size_t)bm0 * lda1 + kt * 64;
      #pragma unroll
      for (int it = 0; it < 8; ++it) {
        int c = it * 256 + tid;
        int row = c >> 4, col = (c & 15) << 2;
        float4 v = *(const float4*)(Ab + (size_t)row * lda1 + col);
        bf16x4 h;
        h[0] = (bf16)v.x; h[1] = (bf16)v.y; h[2] = (bf16)v.z; h[3] = (bf16)v.w;
        *(bf16x4*)&As[row][col] = h;
      }
    } else {
      const bf16* Ab = A2 + (size_t)bm0 * lda2 + (kt - kt1) * 64;
      #pragma unroll
      for (int it = 0; it < 8; ++it) {
        int c = it * 256 + tid;
        int row = c >> 4, col = (c & 15) << 2;
        bf16x4 v = *(const bf16x4*)(Ab + (size_t)row * lda2 + col);
        *(bf16x4*)&As[row][col] = v;
      }
    }
    // ---- stage B tile (128 x 64) ----
    {
      const bf16* Bb = W + (size_t)bn0 * ldb + kt * 64;
      #pragma unroll
      for (int it = 0; it < 8; ++it) {
        int c = it * 256 + tid;
        int row = c >> 4, col = (c & 15) << 2;
        bf16x4 v = *(const bf16x4*)(Bb + (size_t)row * ldb + col);
        *(bf16x4*)&Bs[row][col] = v;
      }
    }
    __syncthreads();
    // ---- compute: 2 K-substeps x 16 MFMA ----
    #pragma unroll
    for (int kk = 0; kk < 2; ++kk) {
      bf16x8 af[4], bfr[4];
      #pragma unroll
      for (int f = 0; f < 4; ++f)
        af[f] = *(const bf16x8*)&As[wr * 64 + f * 16 + lr][kk * 32 + lh * 8];
      #pragma unroll
      for (int f = 0; f < 4; ++f)
        bfr[f] = *(const bf16x8*)&Bs[wc * 64 + f * 16 + lr][kk * 32 + lh * 8];
      #pragma unroll
      for (int fi = 0; fi < 4; ++fi)
        #pragma unroll
        for (int fj = 0; fj < 4; ++fj)
          acc[fi][fj] = __builtin_amdgcn_mfma_f32_16x16x32_bf16(
              af[fi], bfr[fj], acc[fi][fj], 0, 0, 0);
    }
  }
  // ---- epilogue: C/D layout col = lane&15, row = (lane>>4)*4 + r ----
  #pragma unroll
  for (int fi = 0; fi < 4; ++fi)
    #pragma unroll
    for (int fj = 0; fj < 4; ++fj) {
      int row = bm0 + wr * 64 + fi * 16 + lh * 4;
      int col = bn0 + wc * 64 + fj * 16 + lr;
      float* Cp = C + (size_t)row * ldc + col;
      #pragma unroll
      for (int r = 0; r < 4; ++r) Cp[(size_t)r * ldc] = acc[fi][fj][r];
    }
}

// ---------------------------------------------------------------------------
// k2: sequential scan. One WG per batch element, 512 threads (4-way K split).
// A in registers, state ping-pong in LDS, Bx double-buffer-prefetched in
// 32-step (16KB) chunks so HBM latency hides under compute.
// ---------------------------------------------------------------------------
__global__ __launch_bounds__(512) void k2_scan(
    const float* __restrict__ Bx, const float* __restrict__ A,
    bf16* __restrict__ states) {
  __shared__ __align__(16) float st[2][SS];
  __shared__ __align__(16) float part[3][SS];
  __shared__ __align__(16) float bxb[2][32 * SS];

  const int tid = threadIdx.x;
  const int s = tid & 127;
  const int q = tid >> 7;          // 0..3 K-split
  const int b = blockIdx.x;

  float areg[32];
  {
    const float* Ar = A + s * SS + q * 32;
    #pragma unroll
    for (int j = 0; j < 8; ++j) {
      float4 v = *(const float4*)(Ar + j * 4);
      areg[j * 4 + 0] = v.x; areg[j * 4 + 1] = v.y;
      areg[j * 4 + 2] = v.z; areg[j * 4 + 3] = v.w;
    }
  }
  if (tid < SS) st[0][tid] = 0.f;

  const float* Bxb = Bx + (size_t)b * TT * SS;
  {
    float4 c0 = *(const float4*)(Bxb + tid * 4);
    float4 c1 = *(const float4*)(Bxb + 2048 + tid * 4);
    *(float4*)&bxb[0][tid * 4] = c0;
    *(float4*)&bxb[0][2048 + tid * 4] = c1;
  }
  float4 n0 = *(const float4*)(Bxb + 4096 + tid * 4);
  float4 n1 = *(const float4*)(Bxb + 4096 + 2048 + tid * 4);
  __syncthreads();

  bf16* so = states + (size_t)b * TT * SS;
  int p = 0, cur = 0;
  for (int ch = 0; ch < 8; ++ch) {
    #pragma unroll 1
    for (int t2 = 0; t2 < 32; ++t2) {
      const float* stp = st[p];
      float a0 = 0.f, a1 = 0.f, a2 = 0.f, a3 = 0.f;
      #pragma unroll
      for (int j = 0; j < 32; j += 4) {
        float4 sv = *(const float4*)(stp + (q << 5) + j);   // broadcast reads
        a0 += areg[j]     * sv.x;
        a1 += areg[j + 1] * sv.y;
        a2 += areg[j + 2] * sv.z;
        a3 += areg[j + 3] * sv.w;
      }
      float partial = (a0 + a1) + (a2 + a3);
      if (q) part[q - 1][s] = partial;
      __syncthreads();
      if (q == 0) {
        float tot = partial + part[0][s] + part[1][s] + part[2][s]
                  + bxb[cur][t2 * SS + s];
        tot = fminf(10.f, fmaxf(-10.f, tot));
        st[p ^ 1][s] = tot;
        so[(size_t)(ch * 32 + t2) * SS + s] = (bf16)tot;
      }
      __syncthreads();
      p ^= 1;
    }
    if (ch < 7) {
      *(float4*)&bxb[cur ^ 1][tid * 4] = n0;
      *(float4*)&bxb[cur ^ 1][2048 + tid * 4] = n1;
      if (ch < 6) {
        n0 = *(const float4*)(Bxb + (ch + 2) * 4096 + tid * 4);
        n1 = *(const float4*)(Bxb + (ch + 2) * 4096 + 2048 + tid * 4);
      }
      __syncthreads();
      cur ^= 1;
    }
  }
}

// ---------------------------------------------------------------------------
// k4: per-row gate (softmax over 2 = sigmoid of logit diff) + residual mix +
// LayerNorm, in place on d_out. One wave per row, 12 elems/lane.
// ---------------------------------------------------------------------------
__global__ __launch_bounds__(256) void k4_epilogue(
    float* __restrict__ out, const float* __restrict__ x,
    const float* __restrict__ gate_w, const float* __restrict__ gate_b,
    const float* __restrict__ ln_g, const float* __restrict__ ln_b) {
  const int lane = threadIdx.x & 63;
  const int w = threadIdx.x >> 6;
  const int r = blockIdx.x * 4 + w;

  float4* orow = (float4*)(out + (size_t)r * DD);
  const float4* xrow = (const float4*)(x + (size_t)r * DD);
  const float4* g0w = (const float4*)gate_w;
  const float4* g1w = (const float4*)(gate_w + DD);

  float4 o[3], xv[3];
  float d = 0.f;
  #pragma unroll
  for (int i = 0; i < 3; ++i) {
    int c = i * 64 + lane;
    o[i] = orow[c];
    xv[i] = xrow[c];
    float4 w0 = g0w[c], w1 = g1w[c];
    d += xv[i].x * (w0.x - w1.x) + xv[i].y * (w0.y - w1.y)
       + xv[i].z * (w0.z - w1.z) + xv[i].w * (w0.w - w1.w);
  }
  #pragma unroll
  for (int off = 32; off > 0; off >>= 1) d += __shfl_xor(d, off);
  d += gate_b[0] - gate_b[1];
  float g0 = 1.f / (1.f + expf(-d));
  float g1 = 1.f - g0;

  float4 m[3];
  float s1 = 0.f, s2 = 0.f;
  #pragma unroll
  for (int i = 0; i < 3; ++i) {
    m[i].x = g0 * o[i].x + g1 * xv[i].x;
    m[i].y = g0 * o[i].y + g1 * xv[i].y;
    m[i].z = g0 * o[i].z + g1 * xv[i].z;
    m[i].w = g0 * o[i].w + g1 * xv[i].w;
    s1 += (m[i].x + m[i].y) + (m[i].z + m[i].w);
    s2 += (m[i].x * m[i].x + m[i].y * m[i].y)
        + (m[i].z * m[i].z + m[i].w * m[i].w);
  }
  #pragma unroll
  for (int off = 32; off > 0; off >>= 1) {
    s1 += __shfl_xor(s1, off);
    s2 += __shfl_xor(s2, off);
  }
  float mu = s1 * (1.f / 768.f);
  float var = s2 * (1.f / 768.f) - mu * mu;
  float rs = rsqrtf(var + 1e-5f);

  #pragma unroll
  for (int i = 0; i < 3; ++i) {
    int c = i * 64 + lane;
    float4 gg = ((const float4*)ln_g)[c];
    float4 bb = ((const float4*)ln_b)[c];
    float4 y;
    y.x = (m[i].x - mu) * rs * gg.x + bb.x;
    y.y = (m[i].y - mu) * rs * gg.y + bb.y;
    y.z = (m[i].z - mu) * rs * gg.z + bb.z;
    y.w = (m[i].w - mu) * rs * gg.w + bb.w;
    orow[c] = y;
  }
}

// ---------------------------------------------------------------------------
extern "C" void kernel_launch(void* const* d_in, const int* in_sizes, int n_in,
                              void* d_out, int out_size, void* d_ws, size_t ws_size,
                              hipStream_t stream) {
  const float* x   = (const float*)d_in[0];
  const float* A   = (const float*)d_in[1];
  const float* B_w = (const float*)d_in[2];
  const float* C_w = (const float*)d_in[3];
  const float* D_w = (const float*)d_in[4];
  const float* gw  = (const float*)d_in[5];
  const float* gb  = (const float*)d_in[6];
  const float* lng = (const float*)d_in[7];
  const float* lnb = (const float*)d_in[8];
  float* out = (float*)d_out;

  // workspace layout (bf16): W0 [128][768] | W1 [768][896] | states [32768][128]
  bf16* W0 = (bf16*)d_ws;
  bf16* W1 = W0 + SS * DD;
  bf16* states = W1 + DD * KW1;
  // Bx (fp32, 32768x128) lives in the tail of d_out; consumed by k2 before k3
  // overwrites all of d_out.
  float* Bx = out + ((size_t)MM * DD - (size_t)MM * SS);

  // k0: weight conversion (exactly covers 128*768 + 768*896 = 786432 elements)
  k0_convert<<<dim3(3072), dim3(256), 0, stream>>>(B_w, D_w, C_w, W0, W1);

  // k1: Bx = x @ B_w^T   (M=32768, N=128, K=768)
  k_gemm<<<dim3(1, 256), dim3(256), 0, stream>>>(
      x, (const bf16*)nullptr, W0, Bx, 12, 0, DD, 0, DD, SS);

  // k2: sequential scan -> states (bf16)
  k2_scan<<<dim3(128), dim3(512), 0, stream>>>(Bx, A, states);

  // k3: out_raw = x @ D_w^T + states @ C_w^T   (M=32768, N=768, K=896)
  k_gemm<<<dim3(6, 256), dim3(256), 0, stream>>>(
      x, states, W1, out, 12, 2, DD, SS, KW1, DD);

  // k4: gate + residual mix + LayerNorm (in place)
  k4_epilogue<<<dim3(8192), dim3(256), 0, stream>>>(out, x, gw, gb, lng, lnb);
}

// Round 2
// 404.205 us; speedup vs baseline: 1.2769x; 1.2769x over previous
//
#include <hip/hip_runtime.h>
#include <hip/hip_bf16.h>
#include <stdint.h>

typedef __bf16 bf16;
typedef __bf16 bf16x4 __attribute__((ext_vector_type(4)));
typedef __bf16 bf16x8 __attribute__((ext_vector_type(8)));
typedef float  f32x4  __attribute__((ext_vector_type(4)));

static constexpr int BB = 128;   // batch
static constexpr int TT = 256;   // time
static constexpr int DD = 768;   // input dim
static constexpr int SS = 128;   // state dim
static constexpr int MM = BB * TT;          // 32768 rows
static constexpr int KW1 = DD + SS;         // 896 (k3 K)

// async global->LDS, 16B per lane, wave-uniform LDS base + lane*16
__device__ __forceinline__ void gload16(const void* g, void* l) {
  __builtin_amdgcn_global_load_lds(
      (const __attribute__((address_space(1))) void*)(uintptr_t)g,
      (__attribute__((address_space(3))) void*)(uintptr_t)l, 16, 0, 0);
}

// ---------------------------------------------------------------------------
// k0: weight conversion to bf16. W0 = B_w [128][768]; W1 = [D_w | C_w] [768][896]
// ---------------------------------------------------------------------------
__global__ __launch_bounds__(256) void k0_convert(
    const float* __restrict__ B_w, const float* __restrict__ D_w,
    const float* __restrict__ C_w, bf16* __restrict__ W0, bf16* __restrict__ W1) {
  int i = blockIdx.x * 256 + threadIdx.x;           // grid covers exactly 786432
  if (i < SS * DD) {
    W0[i] = (bf16)B_w[i];
  } else {
    int j = i - SS * DD;
    int n = j / KW1;
    int k = j - n * KW1;
    float v = (k < DD) ? D_w[n * DD + k] : C_w[n * SS + (k - DD)];
    W1[j] = (bf16)v;
  }
}

// ---------------------------------------------------------------------------
// k0x: x (fp32, 25.2M elems) -> xb (bf16). One octet of elems per thread.
// ---------------------------------------------------------------------------
__global__ __launch_bounds__(256) void k0x_convert(
    const float* __restrict__ x, bf16* __restrict__ xb) {
  int i = blockIdx.x * 256 + threadIdx.x;   // 12288 blocks: exactly MM*DD/8
  const float4* src = (const float4*)x;
  float4 a = src[i * 2], b = src[i * 2 + 1];
  bf16x8 h;
  h[0] = (bf16)a.x; h[1] = (bf16)a.y; h[2] = (bf16)a.z; h[3] = (bf16)a.w;
  h[4] = (bf16)b.x; h[5] = (bf16)b.y; h[6] = (bf16)b.z; h[7] = (bf16)b.w;
  *(bf16x8*)&xb[i * 8] = h;
}

// ---------------------------------------------------------------------------
// kg<TAG>: bf16 GEMM, m97 structure. C[m][n] = sum_k A[m][k]*W[n][k].
// 128x128 tile, BK=64, 4 waves (2x2), 16x16x32 MFMA, linear LDS,
// global_load_lds width-16 staging. A = kt1 tiles from A1 + kt2 from A2.
// ---------------------------------------------------------------------------
template <int TAG>
__global__ __launch_bounds__(256) void kg(
    const bf16* __restrict__ A1, const bf16* __restrict__ A2,
    const bf16* __restrict__ W, float* __restrict__ C,
    int kt1, int kt2, int lda1, int lda2, int ldb, int ldc) {
  __shared__ __align__(16) bf16 As[128 * 64];
  __shared__ __align__(16) bf16 Bs[128 * 64];

  const int tid = threadIdx.x;
  const int lane = tid & 63;
  const int wv = tid >> 6;
  const int wr = wv >> 1, wc = wv & 1;
  const int lr = lane & 15, lh = lane >> 4;
  const int bn0 = blockIdx.x * 128;
  const int bm0 = blockIdx.y * 128;

  // staging geometry: chunk = 8 rows x 64 cols = 1024B; 4 chunks per wave
  const int l_row = lane >> 3;        // 0..7 within chunk
  const int l_col = (lane & 7) * 8;   // elem offset within row

  f32x4 acc[4][4] = {};
  const int KT = kt1 + kt2;

  for (int kt = 0; kt < KT; ++kt) {
    __syncthreads();
    // ---- stage A tile (128x64) : 4 global_load_lds per wave ----
    {
      const bf16* Ab;
      int lda;
      if (kt < kt1) { Ab = A1 + (size_t)bm0 * lda1 + kt * 64; lda = lda1; }
      else          { Ab = A2 + (size_t)bm0 * lda2 + (kt - kt1) * 64; lda = lda2; }
      #pragma unroll
      for (int it = 0; it < 4; ++it) {
        int c = wv * 4 + it;                       // chunk 0..15
        const bf16* g = Ab + (size_t)(c * 8 + l_row) * lda + l_col;
        gload16(g, &As[c * 512]);
      }
    }
    // ---- stage B tile (128x64) ----
    {
      const bf16* Bb = W + (size_t)bn0 * ldb + kt * 64;
      #pragma unroll
      for (int it = 0; it < 4; ++it) {
        int c = wv * 4 + it;
        const bf16* g = Bb + (size_t)(c * 8 + l_row) * ldb + l_col;
        gload16(g, &Bs[c * 512]);
      }
    }
    __syncthreads();
    // ---- compute: 2 K-substeps x 16 MFMA ----
    #pragma unroll
    for (int kk = 0; kk < 2; ++kk) {
      bf16x8 af[4], bfr[4];
      #pragma unroll
      for (int f = 0; f < 4; ++f)
        af[f] = *(const bf16x8*)&As[(wr * 64 + f * 16 + lr) * 64 + kk * 32 + lh * 8];
      #pragma unroll
      for (int f = 0; f < 4; ++f)
        bfr[f] = *(const bf16x8*)&Bs[(wc * 64 + f * 16 + lr) * 64 + kk * 32 + lh * 8];
      #pragma unroll
      for (int fi = 0; fi < 4; ++fi)
        #pragma unroll
        for (int fj = 0; fj < 4; ++fj)
          acc[fi][fj] = __builtin_amdgcn_mfma_f32_16x16x32_bf16(
              af[fi], bfr[fj], acc[fi][fj], 0, 0, 0);
    }
  }
  // ---- epilogue: C/D layout col = lane&15, row = (lane>>4)*4 + r ----
  #pragma unroll
  for (int fi = 0; fi < 4; ++fi)
    #pragma unroll
    for (int fj = 0; fj < 4; ++fj) {
      int row = bm0 + wr * 64 + fi * 16 + lh * 4;
      int col = bn0 + wc * 64 + fj * 16 + lr;
      float* Cp = C + (size_t)row * ldc + col;
      #pragma unroll
      for (int r = 0; r < 4; ++r) Cp[(size_t)r * ldc] = acc[fi][fj][r];
    }
}

// ---------------------------------------------------------------------------
// legacy GEMM (fallback when ws too small for xb): fp32 A1 staged with convert
// ---------------------------------------------------------------------------
__global__ __launch_bounds__(256) void k_gemm(
    const float* __restrict__ A1, const bf16* __restrict__ A2,
    const bf16* __restrict__ W, float* __restrict__ C,
    int kt1, int kt2, int lda1, int lda2, int ldb, int ldc) {
  __shared__ __align__(16) bf16 As[128][72];
  __shared__ __align__(16) bf16 Bs[128][72];

  const int tid = threadIdx.x;
  const int lane = tid & 63;
  const int wv = tid >> 6;
  const int wr = wv >> 1, wc = wv & 1;
  const int lr = lane & 15, lh = lane >> 4;
  const int bn0 = blockIdx.x * 128;
  const int bm0 = blockIdx.y * 128;

  f32x4 acc[4][4] = {};
  const int KT = kt1 + kt2;

  for (int kt = 0; kt < KT; ++kt) {
    __syncthreads();
    if (kt < kt1) {
      const float* Ab = A1 + (size_t)bm0 * lda1 + kt * 64;
      #pragma unroll
      for (int it = 0; it < 8; ++it) {
        int c = it * 256 + tid;
        int row = c >> 4, col = (c & 15) << 2;
        float4 v = *(const float4*)(Ab + (size_t)row * lda1 + col);
        bf16x4 h;
        h[0] = (bf16)v.x; h[1] = (bf16)v.y; h[2] = (bf16)v.z; h[3] = (bf16)v.w;
        *(bf16x4*)&As[row][col] = h;
      }
    } else {
      const bf16* Ab = A2 + (size_t)bm0 * lda2 + (kt - kt1) * 64;
      #pragma unroll
      for (int it = 0; it < 8; ++it) {
        int c = it * 256 + tid;
        int row = c >> 4, col = (c & 15) << 2;
        bf16x4 v = *(const bf16x4*)(Ab + (size_t)row * lda2 + col);
        *(bf16x4*)&As[row][col] = v;
      }
    }
    {
      const bf16* Bb = W + (size_t)bn0 * ldb + kt * 64;
      #pragma unroll
      for (int it = 0; it < 8; ++it) {
        int c = it * 256 + tid;
        int row = c >> 4, col = (c & 15) << 2;
        bf16x4 v = *(const bf16x4*)(Bb + (size_t)row * ldb + col);
        *(bf16x4*)&Bs[row][col] = v;
      }
    }
    __syncthreads();
    #pragma unroll
    for (int kk = 0; kk < 2; ++kk) {
      bf16x8 af[4], bfr[4];
      #pragma unroll
      for (int f = 0; f < 4; ++f)
        af[f] = *(const bf16x8*)&As[wr * 64 + f * 16 + lr][kk * 32 + lh * 8];
      #pragma unroll
      for (int f = 0; f < 4; ++f)
        bfr[f] = *(const bf16x8*)&Bs[wc * 64 + f * 16 + lr][kk * 32 + lh * 8];
      #pragma unroll
      for (int fi = 0; fi < 4; ++fi)
        #pragma unroll
        for (int fj = 0; fj < 4; ++fj)
          acc[fi][fj] = __builtin_amdgcn_mfma_f32_16x16x32_bf16(
              af[fi], bfr[fj], acc[fi][fj], 0, 0, 0);
    }
  }
  #pragma unroll
  for (int fi = 0; fi < 4; ++fi)
    #pragma unroll
    for (int fj = 0; fj < 4; ++fj) {
      int row = bm0 + wr * 64 + fi * 16 + lh * 4;
      int col = bn0 + wc * 64 + fj * 16 + lr;
      float* Cp = C + (size_t)row * ldc + col;
      #pragma unroll
      for (int r = 0; r < 4; ++r) Cp[(size_t)r * ldc] = acc[fi][fj][r];
    }
}

// ---------------------------------------------------------------------------
// k2: sequential scan. One WG per batch element, 512 threads (4-way K split).
// ---------------------------------------------------------------------------
__global__ __launch_bounds__(512) void k2_scan(
    const float* __restrict__ Bx, const float* __restrict__ A,
    bf16* __restrict__ states) {
  __shared__ __align__(16) float st[2][SS];
  __shared__ __align__(16) float part[3][SS];
  __shared__ __align__(16) float bxb[2][32 * SS];

  const int tid = threadIdx.x;
  const int s = tid & 127;
  const int q = tid >> 7;          // 0..3 K-split
  const int b = blockIdx.x;

  float areg[32];
  {
    const float* Ar = A + s * SS + q * 32;
    #pragma unroll
    for (int j = 0; j < 8; ++j) {
      float4 v = *(const float4*)(Ar + j * 4);
      areg[j * 4 + 0] = v.x; areg[j * 4 + 1] = v.y;
      areg[j * 4 + 2] = v.z; areg[j * 4 + 3] = v.w;
    }
  }
  if (tid < SS) st[0][tid] = 0.f;

  const float* Bxb = Bx + (size_t)b * TT * SS;
  {
    float4 c0 = *(const float4*)(Bxb + tid * 4);
    float4 c1 = *(const float4*)(Bxb + 2048 + tid * 4);
    *(float4*)&bxb[0][tid * 4] = c0;
    *(float4*)&bxb[0][2048 + tid * 4] = c1;
  }
  float4 n0 = *(const float4*)(Bxb + 4096 + tid * 4);
  float4 n1 = *(const float4*)(Bxb + 4096 + 2048 + tid * 4);
  __syncthreads();

  bf16* so = states + (size_t)b * TT * SS;
  int p = 0, cur = 0;
  for (int ch = 0; ch < 8; ++ch) {
    #pragma unroll 1
    for (int t2 = 0; t2 < 32; ++t2) {
      const float* stp = st[p];
      float a0 = 0.f, a1 = 0.f, a2 = 0.f, a3 = 0.f;
      #pragma unroll
      for (int j = 0; j < 32; j += 4) {
        float4 sv = *(const float4*)(stp + (q << 5) + j);   // broadcast reads
        a0 += areg[j]     * sv.x;
        a1 += areg[j + 1] * sv.y;
        a2 += areg[j + 2] * sv.z;
        a3 += areg[j + 3] * sv.w;
      }
      float partial = (a0 + a1) + (a2 + a3);
      if (q) part[q - 1][s] = partial;
      __syncthreads();
      if (q == 0) {
        float tot = partial + part[0][s] + part[1][s] + part[2][s]
                  + bxb[cur][t2 * SS + s];
        tot = fminf(10.f, fmaxf(-10.f, tot));
        st[p ^ 1][s] = tot;
        so[(size_t)(ch * 32 + t2) * SS + s] = (bf16)tot;
      }
      __syncthreads();
      p ^= 1;
    }
    if (ch < 7) {
      *(float4*)&bxb[cur ^ 1][tid * 4] = n0;
      *(float4*)&bxb[cur ^ 1][2048 + tid * 4] = n1;
      if (ch < 6) {
        n0 = *(const float4*)(Bxb + (ch + 2) * 4096 + tid * 4);
        n1 = *(const float4*)(Bxb + (ch + 2) * 4096 + 2048 + tid * 4);
      }
      __syncthreads();
      cur ^= 1;
    }
  }
}

// ---------------------------------------------------------------------------
// k4: per-row gate + residual mix + LayerNorm, in place on d_out.
// ---------------------------------------------------------------------------
__global__ __launch_bounds__(256) void k4_epilogue(
    float* __restrict__ out, const float* __restrict__ x,
    const float* __restrict__ gate_w, const float* __restrict__ gate_b,
    const float* __restrict__ ln_g, const float* __restrict__ ln_b) {
  const int lane = threadIdx.x & 63;
  const int w = threadIdx.x >> 6;
  const int r = blockIdx.x * 4 + w;

  float4* orow = (float4*)(out + (size_t)r * DD);
  const float4* xrow = (const float4*)(x + (size_t)r * DD);
  const float4* g0w = (const float4*)gate_w;
  const float4* g1w = (const float4*)(gate_w + DD);

  float4 o[3], xv[3];
  float d = 0.f;
  #pragma unroll
  for (int i = 0; i < 3; ++i) {
    int c = i * 64 + lane;
    o[i] = orow[c];
    xv[i] = xrow[c];
    float4 w0 = g0w[c], w1 = g1w[c];
    d += xv[i].x * (w0.x - w1.x) + xv[i].y * (w0.y - w1.y)
       + xv[i].z * (w0.z - w1.z) + xv[i].w * (w0.w - w1.w);
  }
  #pragma unroll
  for (int off = 32; off > 0; off >>= 1) d += __shfl_xor(d, off);
  d += gate_b[0] - gate_b[1];
  float g0 = 1.f / (1.f + expf(-d));
  float g1 = 1.f - g0;

  float4 m[3];
  float s1 = 0.f, s2 = 0.f;
  #pragma unroll
  for (int i = 0; i < 3; ++i) {
    m[i].x = g0 * o[i].x + g1 * xv[i].x;
    m[i].y = g0 * o[i].y + g1 * xv[i].y;
    m[i].z = g0 * o[i].z + g1 * xv[i].z;
    m[i].w = g0 * o[i].w + g1 * xv[i].w;
    s1 += (m[i].x + m[i].y) + (m[i].z + m[i].w);
    s2 += (m[i].x * m[i].x + m[i].y * m[i].y)
        + (m[i].z * m[i].z + m[i].w * m[i].w);
  }
  #pragma unroll
  for (int off = 32; off > 0; off >>= 1) {
    s1 += __shfl_xor(s1, off);
    s2 += __shfl_xor(s2, off);
  }
  float mu = s1 * (1.f / 768.f);
  float var = s2 * (1.f / 768.f) - mu * mu;
  float rs = rsqrtf(var + 1e-5f);

  #pragma unroll
  for (int i = 0; i < 3; ++i) {
    int c = i * 64 + lane;
    float4 gg = ((const float4*)ln_g)[c];
    float4 bb = ((const float4*)ln_b)[c];
    float4 y;
    y.x = (m[i].x - mu) * rs * gg.x + bb.x;
    y.y = (m[i].y - mu) * rs * gg.y + bb.y;
    y.z = (m[i].z - mu) * rs * gg.z + bb.z;
    y.w = (m[i].w - mu) * rs * gg.w + bb.w;
    orow[c] = y;
  }
}

// ---------------------------------------------------------------------------
extern "C" void kernel_launch(void* const* d_in, const int* in_sizes, int n_in,
                              void* d_out, int out_size, void* d_ws, size_t ws_size,
                              hipStream_t stream) {
  const float* x   = (const float*)d_in[0];
  const float* A   = (const float*)d_in[1];
  const float* B_w = (const float*)d_in[2];
  const float* C_w = (const float*)d_in[3];
  const float* D_w = (const float*)d_in[4];
  const float* gw  = (const float*)d_in[5];
  const float* gb  = (const float*)d_in[6];
  const float* lng = (const float*)d_in[7];
  const float* lnb = (const float*)d_in[8];
  float* out = (float*)d_out;

  // ws layout (bf16): W0 [128][768] | W1 [768][896] | states [32768][128] | xb [32768][768]
  bf16* W0 = (bf16*)d_ws;
  bf16* W1 = W0 + SS * DD;
  bf16* states = W1 + DD * KW1;
  bf16* xb = states + (size_t)MM * SS;
  const size_t ws_need =
      2ull * (SS * DD + DD * KW1 + (size_t)MM * SS + (size_t)MM * DD);
  // Bx (fp32, 32768x128) in the tail of d_out; consumed by k2 before k3
  // overwrites all of d_out.
  float* Bx = out + ((size_t)MM * DD - (size_t)MM * SS);

  k0_convert<<<dim3(3072), dim3(256), 0, stream>>>(B_w, D_w, C_w, W0, W1);

  if (ws_size >= ws_need) {
    // fast path: bf16 x + global_load_lds GEMMs
    k0x_convert<<<dim3(12288), dim3(256), 0, stream>>>(x, xb);
    kg<1><<<dim3(1, 256), dim3(256), 0, stream>>>(
        xb, (const bf16*)nullptr, W0, Bx, 12, 0, DD, 0, DD, SS);
    k2_scan<<<dim3(128), dim3(512), 0, stream>>>(Bx, A, states);
    kg<3><<<dim3(6, 256), dim3(256), 0, stream>>>(
        xb, states, W1, out, 12, 2, DD, SS, KW1, DD);
  } else {
    // fallback: fp32-A staging (R1 pipeline)
    k_gemm<<<dim3(1, 256), dim3(256), 0, stream>>>(
        x, (const bf16*)nullptr, W0, Bx, 12, 0, DD, 0, DD, SS);
    k2_scan<<<dim3(128), dim3(512), 0, stream>>>(Bx, A, states);
    k_gemm<<<dim3(6, 256), dim3(256), 0, stream>>>(
        x, states, W1, out, 12, 2, DD, SS, KW1, DD);
  }

  k4_epilogue<<<dim3(8192), dim3(256), 0, stream>>>(out, x, gw, gb, lng, lnb);
}